// Round 1
// baseline (141.702 us; speedup 1.0000x reference)
//
#include <hip/hip_runtime.h>
#include <float.h>

// Problem constants (from reference setup_inputs)
#define N_   2
#define C4_  128
#define C_   32      // C4/4
#define H_   100
#define W_   100
#define HW_  10000   // H*W boxes per batch

// One thread per output element. Output layout: [N, C, HW, 4] flat,
// tid = ((n*C + c)*HW + b)*4 + i  -> coalesced stores.
__global__ __launch_bounds__(256) void border_align_kernel(
    const float* __restrict__ feat,    // [N, C4, H, W]
    const float* __restrict__ boxes,   // [N, HW, 4] (x1,y1,x2,y2)
    const int*   __restrict__ pool_ptr,
    float*       __restrict__ out)     // [N, C, HW, 4]
{
    const int tid = blockIdx.x * blockDim.x + threadIdx.x;

    const int i    = tid & 3;           // border: 0=top,1=left,2=bottom,3=right
    int       rest = tid >> 2;
    const int b    = rest % HW_;
    rest /= HW_;
    const int c    = rest % C_;
    const int n    = rest / C_;

    // 4 consecutive lanes (i=0..3) share one box -> broadcast-friendly load
    const float4 box = reinterpret_cast<const float4*>(boxes)[n * HW_ + b];
    const float x1 = box.x, y1 = box.y, x2 = box.z, y2 = box.w;
    const float bw = x2 - x1, bh = y2 - y1;

    // Branch-free per-border parameterization: (x,y) = (bx + ax*t, by + ay*t)
    const float bx = (i < 2) ? x1 : x2;
    const float by = (i < 2) ? y1 : y2;
    const float ax = (i == 0) ? bw : ((i == 2) ? -bw : 0.0f);
    const float ay = (i == 1) ? bh : ((i == 3) ? -bh : 0.0f);

    const int ch = i * C_ + c;  // channel group per border
    const float* __restrict__ fp = feat + (size_t)(n * C4_ + ch) * (H_ * W_);

    const int P = *pool_ptr;    // pool_size (10)

    float acc = -FLT_MAX;
    for (int k = 0; k <= P; ++k) {
        const float t  = (float)k / (float)P;          // match ref: arange/P
        const float xs = bx + ax * t;
        const float ys = by + ay * t;

        const bool valid = (ys > -1.0f) & (ys < (float)H_) &
                           (xs > -1.0f) & (xs < (float)W_);

        float x = fminf(fmaxf(xs, 0.0f), (float)(W_ - 1));
        float y = fminf(fmaxf(ys, 0.0f), (float)(H_ - 1));

        int xl = (int)floorf(x);
        int yl = (int)floorf(y);
        xl = min(max(xl, 0), W_ - 2);
        yl = min(max(yl, 0), H_ - 2);

        const float lx = x - (float)xl;
        const float ly = y - (float)yl;
        const float hx = 1.0f - lx;
        const float hy = 1.0f - ly;

        const float* p00 = fp + yl * W_ + xl;
        const float v00 = p00[0];
        const float v01 = p00[1];
        const float v10 = p00[W_];
        const float v11 = p00[W_ + 1];

        float val = (hy * hx) * v00 + (hy * lx) * v01
                  + (ly * hx) * v10 + (ly * lx) * v11;
        val = valid ? val : 0.0f;
        acc = fmaxf(acc, val);
    }

    out[tid] = acc;
}

extern "C" void kernel_launch(void* const* d_in, const int* in_sizes, int n_in,
                              void* d_out, int out_size, void* d_ws, size_t ws_size,
                              hipStream_t stream) {
    const float* feat  = (const float*)d_in[0];
    const float* boxes = (const float*)d_in[1];
    const int*   ps    = (const int*)d_in[2];
    float*       out   = (float*)d_out;

    const int total = N_ * C_ * HW_ * 4;   // 2,560,000
    const int block = 256;
    const int grid  = total / block;       // 10,000 (divides exactly)
    border_align_kernel<<<grid, block, 0, stream>>>(feat, boxes, ps, out);
}

// Round 2
// 38.709 us; speedup vs baseline: 3.6607x; 3.6607x over previous
//
#include <hip/hip_runtime.h>
#include <float.h>

// Problem constants (from reference setup_inputs)
#define N_   2
#define C4_  128
#define C_   32      // C4/4
#define H_   100
#define W_   100
#define HW_  10000   // H*W boxes per batch (also H*W positions)

// ---------------------------------------------------------------------------
// Pass 1: transpose feat [N, C4, H, W] -> fT [N*4][HW][32]
// (group g = n*4 + border_i holds channels [i*32, i*32+32) of batch n,
//  channel-contiguous per spatial position -> coalesced gathers in pass 2)
// ---------------------------------------------------------------------------
__global__ __launch_bounds__(256) void transpose_kernel(
    const float* __restrict__ feat, float* __restrict__ fT)
{
    __shared__ float tile[32][33];
    const int g  = blockIdx.y;          // 0..7  (n*4 + i)
    const int p0 = blockIdx.x * 32;     // position tile base
    const int tx = threadIdx.x;         // 0..31
    const int ty = threadIdx.y;         // 0..7

    const float* src = feat + (size_t)g * 32 * HW_;  // == (n*C4 + i*32)*HW
    #pragma unroll
    for (int cc = 0; cc < 32; cc += 8) {
        const int c = cc + ty;
        const int p = p0 + tx;
        tile[c][tx] = (p < HW_) ? src[(size_t)c * HW_ + p] : 0.0f;
    }
    __syncthreads();
    float* dst = fT + (size_t)g * HW_ * 32;
    #pragma unroll
    for (int pp = 0; pp < 32; pp += 8) {
        const int p = p0 + pp + ty;
        if (p < HW_) dst[(size_t)p * 32 + tx] = tile[tx][pp + ty];
    }
}

// ---------------------------------------------------------------------------
// Pass 2: border-align on transposed features.
// Block = 256 threads = 2 boxes x 4 borders x 32 channels.
// Lane layout: c = t&31 (fastest), i = (t>>5)&3, bb = t>>7.
// Each bilinear corner load: 32 lanes read 32 consecutive floats (128B seg).
// ---------------------------------------------------------------------------
#define SAMPLE(TT)                                                            \
    {                                                                         \
        const float tt = (TT);                                                \
        const float xs = bx + ax * tt;                                        \
        const float ys = by + ay * tt;                                        \
        const bool valid = (ys > -1.0f) & (ys < (float)H_) &                  \
                           (xs > -1.0f) & (xs < (float)W_);                   \
        float x = fminf(fmaxf(xs, 0.0f), (float)(W_ - 1));                    \
        float y = fminf(fmaxf(ys, 0.0f), (float)(H_ - 1));                    \
        int xl = min(max((int)floorf(x), 0), W_ - 2);                         \
        int yl = min(max((int)floorf(y), 0), H_ - 2);                         \
        const float lx = x - (float)xl;                                       \
        const float ly = y - (float)yl;                                       \
        const float hx = 1.0f - lx;                                           \
        const float hy = 1.0f - ly;                                           \
        const float* p00 = fp + (size_t)(yl * W_ + xl) * 32;                  \
        const float v00 = p00[0];                                             \
        const float v01 = p00[32];                                            \
        const float v10 = p00[W_ * 32];                                       \
        const float v11 = p00[(W_ + 1) * 32];                                 \
        float val = (hy * hx) * v00 + (hy * lx) * v01                         \
                  + (ly * hx) * v10 + (ly * lx) * v11;                        \
        val = valid ? val : 0.0f;                                             \
        acc = fmaxf(acc, val);                                                \
    }

__global__ __launch_bounds__(256) void border_align_t_kernel(
    const float* __restrict__ fT,      // [N*4][HW][32]
    const float* __restrict__ boxes,   // [N, HW, 4]
    const int*   __restrict__ pool_ptr,
    float*       __restrict__ out)     // [N, C, HW, 4]
{
    const int t  = threadIdx.x;
    const int c  = t & 31;
    const int i  = (t >> 5) & 3;
    const int bb = t >> 7;                      // 0..1 local box
    const int B  = blockIdx.x * 2 + bb;         // global box in [0, N*HW)
    const int n  = B / HW_;
    const int b  = B - n * HW_;
    (void)b;

    const float4 box = reinterpret_cast<const float4*>(boxes)[B];
    const float x1 = box.x, y1 = box.y, x2 = box.z, y2 = box.w;
    const float bw = x2 - x1, bh = y2 - y1;

    const float bx = (i < 2) ? x1 : x2;
    const float by = (i < 2) ? y1 : y2;
    const float ax = (i == 0) ? bw : ((i == 2) ? -bw : 0.0f);
    const float ay = (i == 1) ? bh : ((i == 3) ? -bh : 0.0f);

    const float* __restrict__ fp = fT + ((size_t)(n * 4 + i) * HW_) * 32 + c;

    const int P = *pool_ptr;
    float acc = -FLT_MAX;
    if (P == 10) {
        #pragma unroll
        for (int k = 0; k <= 10; ++k) SAMPLE((float)k / 10.0f);
    } else {
        for (int k = 0; k <= P; ++k) SAMPLE((float)k / (float)P);
    }

    // LDS shuffle so stores are (b,i)-contiguous per channel.
    __shared__ float sval[32 * 9];              // stride 9 avoids conflicts
    sval[c * 9 + bb * 4 + i] = acc;
    __syncthreads();

    const int cs = t >> 3;                      // 0..31 channel
    const int q  = t & 7;                       // 0..7 = (bb,i) pairs
    const int B0 = blockIdx.x * 2;              // first box of block
    const int n0 = B0 / HW_;
    const int b0 = B0 - n0 * HW_;
    out[((size_t)(n0 * C_ + cs) * HW_ + b0) * 4 + q] = sval[cs * 9 + q];
}

// ---------------------------------------------------------------------------
// Fallback (round-1 kernel) if workspace is too small for the transpose.
// ---------------------------------------------------------------------------
__global__ __launch_bounds__(256) void border_align_kernel(
    const float* __restrict__ feat, const float* __restrict__ boxes,
    const int* __restrict__ pool_ptr, float* __restrict__ out)
{
    const int tid = blockIdx.x * blockDim.x + threadIdx.x;
    const int i    = tid & 3;
    int       rest = tid >> 2;
    const int b    = rest % HW_;
    rest /= HW_;
    const int c    = rest % C_;
    const int n    = rest / C_;

    const float4 box = reinterpret_cast<const float4*>(boxes)[n * HW_ + b];
    const float x1 = box.x, y1 = box.y, x2 = box.z, y2 = box.w;
    const float bw = x2 - x1, bh = y2 - y1;
    const float bx = (i < 2) ? x1 : x2;
    const float by = (i < 2) ? y1 : y2;
    const float ax = (i == 0) ? bw : ((i == 2) ? -bw : 0.0f);
    const float ay = (i == 1) ? bh : ((i == 3) ? -bh : 0.0f);
    const int ch = i * C_ + c;
    const float* __restrict__ fp = feat + (size_t)(n * C4_ + ch) * (H_ * W_);
    const int P = *pool_ptr;
    float acc = -FLT_MAX;
    for (int k = 0; k <= P; ++k) {
        const float tt = (float)k / (float)P;
        const float xs = bx + ax * tt;
        const float ys = by + ay * tt;
        const bool valid = (ys > -1.0f) & (ys < (float)H_) &
                           (xs > -1.0f) & (xs < (float)W_);
        float x = fminf(fmaxf(xs, 0.0f), (float)(W_ - 1));
        float y = fminf(fmaxf(ys, 0.0f), (float)(H_ - 1));
        int xl = min(max((int)floorf(x), 0), W_ - 2);
        int yl = min(max((int)floorf(y), 0), H_ - 2);
        const float lx = x - (float)xl, ly = y - (float)yl;
        const float hx = 1.0f - lx, hy = 1.0f - ly;
        const float* p00 = fp + yl * W_ + xl;
        float val = (hy * hx) * p00[0] + (hy * lx) * p00[1]
                  + (ly * hx) * p00[W_] + (ly * lx) * p00[W_ + 1];
        val = valid ? val : 0.0f;
        acc = fmaxf(acc, val);
    }
    out[tid] = acc;
}

extern "C" void kernel_launch(void* const* d_in, const int* in_sizes, int n_in,
                              void* d_out, int out_size, void* d_ws, size_t ws_size,
                              hipStream_t stream) {
    const float* feat  = (const float*)d_in[0];
    const float* boxes = (const float*)d_in[1];
    const int*   ps    = (const int*)d_in[2];
    float*       out   = (float*)d_out;

    const size_t needed = (size_t)N_ * 4 * HW_ * 32 * sizeof(float); // 10.24 MB
    if (ws_size >= needed) {
        float* fT = (float*)d_ws;
        transpose_kernel<<<dim3((HW_ + 31) / 32, N_ * 4), dim3(32, 8), 0, stream>>>(feat, fT);
        border_align_t_kernel<<<(N_ * HW_) / 2, 256, 0, stream>>>(fT, boxes, ps, out);
    } else {
        const int total = N_ * C_ * HW_ * 4;
        border_align_kernel<<<total / 256, 256, 0, stream>>>(feat, boxes, ps, out);
    }
}

// Round 3
// 34.648 us; speedup vs baseline: 4.0897x; 1.1172x over previous
//
#include <hip/hip_runtime.h>
#include <float.h>

// Problem constants (from reference setup_inputs)
#define N_   2
#define C4_  128
#define C_   32      // C4/4
#define H_   100
#define W_   100
#define HW_  10000   // H*W boxes per batch (also H*W positions)

// ---------------------------------------------------------------------------
// Pass 1: transpose feat [N, C4, H, W] -> fT [N*4][HW][32]
// (group g = n*4 + border_i holds channels [i*32, i*32+32) of batch n,
//  channel-contiguous per spatial position -> coalesced gathers in pass 2)
// ---------------------------------------------------------------------------
__global__ __launch_bounds__(256) void transpose_kernel(
    const float* __restrict__ feat, float* __restrict__ fT)
{
    __shared__ float tile[32][33];
    const int g  = blockIdx.y;          // 0..7  (n*4 + i)
    const int p0 = blockIdx.x * 32;     // position tile base
    const int tx = threadIdx.x;         // 0..31
    const int ty = threadIdx.y;         // 0..7

    const float* src = feat + (size_t)g * 32 * HW_;  // == (n*C4 + i*32)*HW
    #pragma unroll
    for (int cc = 0; cc < 32; cc += 8) {
        const int c = cc + ty;
        const int p = p0 + tx;
        tile[c][tx] = (p < HW_) ? src[(size_t)c * HW_ + p] : 0.0f;
    }
    __syncthreads();
    float* dst = fT + (size_t)g * HW_ * 32;
    #pragma unroll
    for (int pp = 0; pp < 32; pp += 8) {
        const int p = p0 + pp + ty;
        if (p < HW_) dst[(size_t)p * 32 + tx] = tile[tx][pp + ty];
    }
}

// ---------------------------------------------------------------------------
// Pass 2: border-align, float4 over channels.
// Block = 256 threads = 8 boxes x 4 borders x 8 channel-quads.
// Lane layout: v = t&7 (channel quad), i = (t>>3)&3 (border), bb = t>>5 (box).
// Each corner load: 8 lanes x float4 = 128B contiguous segment.
// ---------------------------------------------------------------------------
#define SAMPLE4(TT)                                                           \
    {                                                                         \
        const float tt = (TT);                                                \
        const float xs = bx + ax * tt;                                        \
        const float ys = by + ay * tt;                                        \
        const bool valid = (ys > -1.0f) & (ys < (float)H_) &                  \
                           (xs > -1.0f) & (xs < (float)W_);                   \
        float x = fminf(fmaxf(xs, 0.0f), (float)(W_ - 1));                    \
        float y = fminf(fmaxf(ys, 0.0f), (float)(H_ - 1));                    \
        int xl = min(max((int)floorf(x), 0), W_ - 2);                         \
        int yl = min(max((int)floorf(y), 0), H_ - 2);                         \
        const float lx = x - (float)xl;                                       \
        const float ly = y - (float)yl;                                       \
        const float hx = 1.0f - lx;                                           \
        const float hy = 1.0f - ly;                                           \
        const float w00 = hy * hx, w01 = hy * lx;                             \
        const float w10 = ly * hx, w11 = ly * lx;                             \
        const size_t cell = (size_t)(yl * W_ + xl) * 8;                       \
        const float4 v00 = fp4[cell];                                         \
        const float4 v01 = fp4[cell + 8];                                     \
        const float4 v10 = fp4[cell + W_ * 8];                                \
        const float4 v11 = fp4[cell + (W_ + 1) * 8];                          \
        float4 val;                                                           \
        val.x = w00 * v00.x + w01 * v01.x + w10 * v10.x + w11 * v11.x;        \
        val.y = w00 * v00.y + w01 * v01.y + w10 * v10.y + w11 * v11.y;        \
        val.z = w00 * v00.z + w01 * v01.z + w10 * v10.z + w11 * v11.z;        \
        val.w = w00 * v00.w + w01 * v01.w + w10 * v10.w + w11 * v11.w;        \
        if (!valid) { val.x = 0.0f; val.y = 0.0f; val.z = 0.0f; val.w = 0.0f; } \
        acc.x = fmaxf(acc.x, val.x);                                          \
        acc.y = fmaxf(acc.y, val.y);                                          \
        acc.z = fmaxf(acc.z, val.z);                                          \
        acc.w = fmaxf(acc.w, val.w);                                          \
    }

__global__ __launch_bounds__(256) void border_align_t4_kernel(
    const float* __restrict__ fT,      // [N*4][HW][32]
    const float* __restrict__ boxes,   // [N, HW, 4]
    const int*   __restrict__ pool_ptr,
    float*       __restrict__ out)     // [N, C, HW, 4]
{
    const int t  = threadIdx.x;
    const int v  = t & 7;                       // channel quad (c = 4v..4v+3)
    const int i  = (t >> 3) & 3;                // border
    const int bb = t >> 5;                      // 0..7 local box
    const int B  = blockIdx.x * 8 + bb;         // global box in [0, N*HW)
    const int n  = B / HW_;                     // HW_ % 8 == 0 -> block never spans n

    const float4 box = reinterpret_cast<const float4*>(boxes)[B];
    const float x1 = box.x, y1 = box.y, x2 = box.z, y2 = box.w;
    const float bw = x2 - x1, bh = y2 - y1;

    const float bx = (i < 2) ? x1 : x2;
    const float by = (i < 2) ? y1 : y2;
    const float ax = (i == 0) ? bw : ((i == 2) ? -bw : 0.0f);
    const float ay = (i == 1) ? bh : ((i == 3) ? -bh : 0.0f);

    const float4* __restrict__ fp4 =
        reinterpret_cast<const float4*>(fT + (size_t)(n * 4 + i) * HW_ * 32) + v;

    const int P = *pool_ptr;
    float4 acc = make_float4(-FLT_MAX, -FLT_MAX, -FLT_MAX, -FLT_MAX);
    if (P == 10) {
        #pragma unroll
        for (int k = 0; k <= 10; ++k) SAMPLE4((float)k / 10.0f);
    } else {
        for (int k = 0; k <= P; ++k) SAMPLE4((float)k / (float)P);
    }

    // LDS shuffle: sval[channel][bb*4+i], row padded to 36 (float4-aligned).
    __shared__ float sval[32 * 36];
    {
        const int col = bb * 4 + i;
        sval[(4 * v + 0) * 36 + col] = acc.x;
        sval[(4 * v + 1) * 36 + col] = acc.y;
        sval[(4 * v + 2) * 36 + col] = acc.z;
        sval[(4 * v + 3) * 36 + col] = acc.w;
    }
    __syncthreads();

    // Store: thread t -> channel cs = t>>3, box q = t&7 (4 borders = float4).
    const int cs = t >> 3;
    const int q  = t & 7;
    const float4 o = *reinterpret_cast<const float4*>(&sval[cs * 36 + q * 4]);
    const int B0 = blockIdx.x * 8;
    const int n0 = B0 / HW_;
    const int b0 = B0 - n0 * HW_;
    float4* out4 = reinterpret_cast<float4*>(out);
    out4[(size_t)(n0 * C_ + cs) * HW_ + b0 + q] = o;
}

// ---------------------------------------------------------------------------
// Fallback (round-1 kernel) if workspace is too small for the transpose.
// ---------------------------------------------------------------------------
__global__ __launch_bounds__(256) void border_align_kernel(
    const float* __restrict__ feat, const float* __restrict__ boxes,
    const int* __restrict__ pool_ptr, float* __restrict__ out)
{
    const int tid = blockIdx.x * blockDim.x + threadIdx.x;
    const int i    = tid & 3;
    int       rest = tid >> 2;
    const int b    = rest % HW_;
    rest /= HW_;
    const int c    = rest % C_;
    const int n    = rest / C_;

    const float4 box = reinterpret_cast<const float4*>(boxes)[n * HW_ + b];
    const float x1 = box.x, y1 = box.y, x2 = box.z, y2 = box.w;
    const float bw = x2 - x1, bh = y2 - y1;
    const float bx = (i < 2) ? x1 : x2;
    const float by = (i < 2) ? y1 : y2;
    const float ax = (i == 0) ? bw : ((i == 2) ? -bw : 0.0f);
    const float ay = (i == 1) ? bh : ((i == 3) ? -bh : 0.0f);
    const int ch = i * C_ + c;
    const float* __restrict__ fp = feat + (size_t)(n * C4_ + ch) * (H_ * W_);
    const int P = *pool_ptr;
    float acc = -FLT_MAX;
    for (int k = 0; k <= P; ++k) {
        const float tt = (float)k / (float)P;
        const float xs = bx + ax * tt;
        const float ys = by + ay * tt;
        const bool valid = (ys > -1.0f) & (ys < (float)H_) &
                           (xs > -1.0f) & (xs < (float)W_);
        float x = fminf(fmaxf(xs, 0.0f), (float)(W_ - 1));
        float y = fminf(fmaxf(ys, 0.0f), (float)(H_ - 1));
        int xl = min(max((int)floorf(x), 0), W_ - 2);
        int yl = min(max((int)floorf(y), 0), H_ - 2);
        const float lx = x - (float)xl, ly = y - (float)yl;
        const float hx = 1.0f - lx, hy = 1.0f - ly;
        const float* p00 = fp + yl * W_ + xl;
        float val = (hy * hx) * p00[0] + (hy * lx) * p00[1]
                  + (ly * hx) * p00[W_] + (ly * lx) * p00[W_ + 1];
        val = valid ? val : 0.0f;
        acc = fmaxf(acc, val);
    }
    out[tid] = acc;
}

extern "C" void kernel_launch(void* const* d_in, const int* in_sizes, int n_in,
                              void* d_out, int out_size, void* d_ws, size_t ws_size,
                              hipStream_t stream) {
    const float* feat  = (const float*)d_in[0];
    const float* boxes = (const float*)d_in[1];
    const int*   ps    = (const int*)d_in[2];
    float*       out   = (float*)d_out;

    const size_t needed = (size_t)N_ * 4 * HW_ * 32 * sizeof(float); // 10.24 MB
    if (ws_size >= needed) {
        float* fT = (float*)d_ws;
        transpose_kernel<<<dim3((HW_ + 31) / 32, N_ * 4), dim3(32, 8), 0, stream>>>(feat, fT);
        border_align_t4_kernel<<<(N_ * HW_) / 8, 256, 0, stream>>>(fT, boxes, ps, out);
    } else {
        const int total = N_ * C_ * HW_ * 4;
        border_align_kernel<<<total / 256, 256, 0, stream>>>(feat, boxes, ps, out);
    }
}

// Round 4
// 30.095 us; speedup vs baseline: 4.7085x; 1.1513x over previous
//
#include <hip/hip_runtime.h>
#include <hip/hip_fp16.h>
#include <float.h>

// Problem constants (from reference setup_inputs)
#define N_   2
#define C4_  128
#define C_   32      // C4/4
#define H_   100
#define W_   100
#define HW_  10000   // H*W boxes per batch (also H*W positions)

// ---------------------------------------------------------------------------
// Pass 1: transpose + compress feat [N, C4, H, W] (fp32) -> fT [N*4][HW][32] (fp16)
// group g = n*4 + border_i holds channels [i*32, i*32+32) of batch n,
// channel-contiguous per spatial position -> one 64B line per bilinear cell.
// ---------------------------------------------------------------------------
__global__ __launch_bounds__(256) void transpose_half_kernel(
    const float* __restrict__ feat, __half* __restrict__ fT)
{
    __shared__ float tile[32][33];
    const int g  = blockIdx.y;          // 0..7  (n*4 + i)
    const int p0 = blockIdx.x * 32;     // position tile base
    const int tx = threadIdx.x;         // 0..31
    const int ty = threadIdx.y;         // 0..7

    const float* src = feat + (size_t)g * 32 * HW_;  // == (n*C4 + i*32)*HW
    #pragma unroll
    for (int cc = 0; cc < 32; cc += 8) {
        const int c = cc + ty;
        const int p = p0 + tx;
        tile[c][tx] = (p < HW_) ? src[(size_t)c * HW_ + p] : 0.0f;
    }
    __syncthreads();

    // Write: each thread emits half2 (channel pair) -> 64B per 16 lanes.
    const int t    = ty * 32 + tx;      // 0..255
    const int pair = t & 15;            // channel pair (2*pair, 2*pair+1)
    const int prow = t >> 4;            // 0..15 local position
    __half2* dst = reinterpret_cast<__half2*>(fT + (size_t)g * HW_ * 32);
    #pragma unroll
    for (int pp = 0; pp < 32; pp += 16) {
        const int p = p0 + prow + pp;
        if (p < HW_) {
            const float a = tile[2 * pair][prow + pp];
            const float b = tile[2 * pair + 1][prow + pp];
            dst[(size_t)p * 16 + pair] = __floats2half2_rn(a, b);
        }
    }
}

// ---------------------------------------------------------------------------
// Pass 2: border-align on fp16 transposed features, 4 channels per thread.
// Block = 256 threads = 8 boxes x 4 borders x 8 channel-quads.
// Lane layout: v = t&7 (channel quad), i = (t>>3)&3 (border), bb = t>>5 (box).
// Each corner load: 8 lanes x uint2(8B) = 64B contiguous segment = 1 line.
// ---------------------------------------------------------------------------
union H4 { uint2 u; __half2 h[2]; };

#define SAMPLE4H(TT)                                                          \
    {                                                                         \
        const float tt = (TT);                                                \
        const float xs = bx + ax * tt;                                        \
        const float ys = by + ay * tt;                                        \
        const bool valid = (ys > -1.0f) & (ys < (float)H_) &                  \
                           (xs > -1.0f) & (xs < (float)W_);                   \
        float x = fminf(fmaxf(xs, 0.0f), (float)(W_ - 1));                    \
        float y = fminf(fmaxf(ys, 0.0f), (float)(H_ - 1));                    \
        int xl = min(max((int)floorf(x), 0), W_ - 2);                         \
        int yl = min(max((int)floorf(y), 0), H_ - 2);                         \
        const float lx = x - (float)xl;                                       \
        const float ly = y - (float)yl;                                       \
        const float hx = 1.0f - lx;                                           \
        const float hy = 1.0f - ly;                                           \
        const float w00 = hy * hx, w01 = hy * lx;                             \
        const float w10 = ly * hx, w11 = ly * lx;                             \
        const size_t cell = (size_t)(yl * W_ + xl) * 8;                       \
        H4 q00, q01, q10, q11;                                                \
        q00.u = fpu[cell];                                                    \
        q01.u = fpu[cell + 8];                                                \
        q10.u = fpu[cell + W_ * 8];                                           \
        q11.u = fpu[cell + (W_ + 1) * 8];                                     \
        const float2 a0 = __half22float2(q00.h[0]);                           \
        const float2 a1 = __half22float2(q00.h[1]);                           \
        const float2 b0 = __half22float2(q01.h[0]);                           \
        const float2 b1 = __half22float2(q01.h[1]);                           \
        const float2 c0 = __half22float2(q10.h[0]);                           \
        const float2 c1 = __half22float2(q10.h[1]);                           \
        const float2 d0 = __half22float2(q11.h[0]);                           \
        const float2 d1 = __half22float2(q11.h[1]);                           \
        float4 val;                                                           \
        val.x = w00 * a0.x + w01 * b0.x + w10 * c0.x + w11 * d0.x;            \
        val.y = w00 * a0.y + w01 * b0.y + w10 * c0.y + w11 * d0.y;            \
        val.z = w00 * a1.x + w01 * b1.x + w10 * c1.x + w11 * d1.x;            \
        val.w = w00 * a1.y + w01 * b1.y + w10 * c1.y + w11 * d1.y;            \
        if (!valid) { val.x = 0.0f; val.y = 0.0f; val.z = 0.0f; val.w = 0.0f; } \
        acc.x = fmaxf(acc.x, val.x);                                          \
        acc.y = fmaxf(acc.y, val.y);                                          \
        acc.z = fmaxf(acc.z, val.z);                                          \
        acc.w = fmaxf(acc.w, val.w);                                          \
    }

__global__ __launch_bounds__(256) void border_align_h4_kernel(
    const __half* __restrict__ fT,     // [N*4][HW][32] fp16
    const float*  __restrict__ boxes,  // [N, HW, 4]
    const int*    __restrict__ pool_ptr,
    float*        __restrict__ out)    // [N, C, HW, 4]
{
    const int t  = threadIdx.x;
    const int v  = t & 7;                       // channel quad (c = 4v..4v+3)
    const int i  = (t >> 3) & 3;                // border
    const int bb = t >> 5;                      // 0..7 local box
    const int B  = blockIdx.x * 8 + bb;         // global box in [0, N*HW)
    const int n  = B / HW_;                     // HW_ % 8 == 0 -> no n-split

    const float4 box = reinterpret_cast<const float4*>(boxes)[B];
    const float x1 = box.x, y1 = box.y, x2 = box.z, y2 = box.w;
    const float bw = x2 - x1, bh = y2 - y1;

    const float bx = (i < 2) ? x1 : x2;
    const float by = (i < 2) ? y1 : y2;
    const float ax = (i == 0) ? bw : ((i == 2) ? -bw : 0.0f);
    const float ay = (i == 1) ? bh : ((i == 3) ? -bh : 0.0f);

    // plane base in uint2 (8B) units; v selects the channel quad
    const uint2* __restrict__ fpu =
        reinterpret_cast<const uint2*>(fT + (size_t)(n * 4 + i) * HW_ * 32) + v;

    const int P = *pool_ptr;
    float4 acc = make_float4(-FLT_MAX, -FLT_MAX, -FLT_MAX, -FLT_MAX);
    if (P == 10) {
        #pragma unroll
        for (int k = 0; k <= 10; ++k) SAMPLE4H((float)k / 10.0f);
    } else {
        for (int k = 0; k <= P; ++k) SAMPLE4H((float)k / (float)P);
    }

    // LDS shuffle: sval[channel][bb*4+i], row padded to 36 (float4-aligned).
    __shared__ float sval[32 * 36];
    {
        const int col = bb * 4 + i;
        sval[(4 * v + 0) * 36 + col] = acc.x;
        sval[(4 * v + 1) * 36 + col] = acc.y;
        sval[(4 * v + 2) * 36 + col] = acc.z;
        sval[(4 * v + 3) * 36 + col] = acc.w;
    }
    __syncthreads();

    // Store: thread t -> channel cs = t>>3, box q = t&7 (4 borders = float4).
    const int cs = t >> 3;
    const int q  = t & 7;
    const float4 o = *reinterpret_cast<const float4*>(&sval[cs * 36 + q * 4]);
    const int B0 = blockIdx.x * 8;
    const int n0 = B0 / HW_;
    const int b0 = B0 - n0 * HW_;
    float4* out4 = reinterpret_cast<float4*>(out);
    out4[(size_t)(n0 * C_ + cs) * HW_ + b0 + q] = o;
}

// ---------------------------------------------------------------------------
// Fallback (round-1 kernel) if workspace is too small for the transpose.
// ---------------------------------------------------------------------------
__global__ __launch_bounds__(256) void border_align_kernel(
    const float* __restrict__ feat, const float* __restrict__ boxes,
    const int* __restrict__ pool_ptr, float* __restrict__ out)
{
    const int tid = blockIdx.x * blockDim.x + threadIdx.x;
    const int i    = tid & 3;
    int       rest = tid >> 2;
    const int b    = rest % HW_;
    rest /= HW_;
    const int c    = rest % C_;
    const int n    = rest / C_;

    const float4 box = reinterpret_cast<const float4*>(boxes)[n * HW_ + b];
    const float x1 = box.x, y1 = box.y, x2 = box.z, y2 = box.w;
    const float bw = x2 - x1, bh = y2 - y1;
    const float bx = (i < 2) ? x1 : x2;
    const float by = (i < 2) ? y1 : y2;
    const float ax = (i == 0) ? bw : ((i == 2) ? -bw : 0.0f);
    const float ay = (i == 1) ? bh : ((i == 3) ? -bh : 0.0f);
    const int ch = i * C_ + c;
    const float* __restrict__ fp = feat + (size_t)(n * C4_ + ch) * (H_ * W_);
    const int P = *pool_ptr;
    float acc = -FLT_MAX;
    for (int k = 0; k <= P; ++k) {
        const float tt = (float)k / (float)P;
        const float xs = bx + ax * tt;
        const float ys = by + ay * tt;
        const bool valid = (ys > -1.0f) & (ys < (float)H_) &
                           (xs > -1.0f) & (xs < (float)W_);
        float x = fminf(fmaxf(xs, 0.0f), (float)(W_ - 1));
        float y = fminf(fmaxf(ys, 0.0f), (float)(H_ - 1));
        int xl = min(max((int)floorf(x), 0), W_ - 2);
        int yl = min(max((int)floorf(y), 0), H_ - 2);
        const float lx = x - (float)xl, ly = y - (float)yl;
        const float hx = 1.0f - lx, hy = 1.0f - ly;
        const float* p00 = fp + yl * W_ + xl;
        float val = (hy * hx) * p00[0] + (hy * lx) * p00[1]
                  + (ly * hx) * p00[W_] + (ly * lx) * p00[W_ + 1];
        val = valid ? val : 0.0f;
        acc = fmaxf(acc, val);
    }
    out[tid] = acc;
}

extern "C" void kernel_launch(void* const* d_in, const int* in_sizes, int n_in,
                              void* d_out, int out_size, void* d_ws, size_t ws_size,
                              hipStream_t stream) {
    const float* feat  = (const float*)d_in[0];
    const float* boxes = (const float*)d_in[1];
    const int*   ps    = (const int*)d_in[2];
    float*       out   = (float*)d_out;

    const size_t needed = (size_t)N_ * 4 * HW_ * 32 * sizeof(__half); // 5.12 MB
    if (ws_size >= needed) {
        __half* fT = (__half*)d_ws;
        transpose_half_kernel<<<dim3((HW_ + 31) / 32, N_ * 4), dim3(32, 8), 0, stream>>>(feat, fT);
        border_align_h4_kernel<<<(N_ * HW_) / 8, 256, 0, stream>>>(fT, boxes, ps, out);
    } else {
        const int total = N_ * C_ * HW_ * 4;
        border_align_kernel<<<total / 256, 256, 0, stream>>>(feat, boxes, ps, out);
    }
}

// Round 5
// 28.467 us; speedup vs baseline: 4.9778x; 1.0572x over previous
//
#include <hip/hip_runtime.h>
#include <hip/hip_fp16.h>
#include <float.h>

// Problem constants (from reference setup_inputs)
#define N_   2
#define C4_  128
#define C_   32      // C4/4
#define H_   100
#define W_   100
#define HW_  10000   // H*W boxes per batch (also H*W positions)
#define NXCD 8

// ---------------------------------------------------------------------------
// Pass 1: transpose + compress feat [N, C4, H, W] (fp32) -> fT [N*4][HW][32] (fp16)
// ---------------------------------------------------------------------------
__global__ __launch_bounds__(256) void transpose_half_kernel(
    const float* __restrict__ feat, __half* __restrict__ fT)
{
    __shared__ float tile[32][33];
    const int g  = blockIdx.y;          // 0..7  (n*4 + i)
    const int p0 = blockIdx.x * 32;     // position tile base
    const int tx = threadIdx.x;         // 0..31
    const int ty = threadIdx.y;         // 0..7

    const float* src = feat + (size_t)g * 32 * HW_;  // == (n*C4 + i*32)*HW
    #pragma unroll
    for (int cc = 0; cc < 32; cc += 8) {
        const int c = cc + ty;
        const int p = p0 + tx;
        tile[c][tx] = (p < HW_) ? src[(size_t)c * HW_ + p] : 0.0f;
    }
    __syncthreads();

    const int t    = ty * 32 + tx;      // 0..255
    const int pair = t & 15;            // channel pair (2*pair, 2*pair+1)
    const int prow = t >> 4;            // 0..15 local position
    __half2* dst = reinterpret_cast<__half2*>(fT + (size_t)g * HW_ * 32);
    #pragma unroll
    for (int pp = 0; pp < 32; pp += 16) {
        const int p = p0 + prow + pp;
        if (p < HW_) {
            const float a = tile[2 * pair][prow + pp];
            const float b = tile[2 * pair + 1][prow + pp];
            dst[(size_t)p * 16 + pair] = __floats2half2_rn(a, b);
        }
    }
}

// ---------------------------------------------------------------------------
// Pass 2: border-align on fp16 transposed features, 4 channels per thread.
// Block = 256 threads = 8 boxes x 4 borders x 8 channel-quads.
// XCD-affinity: blockIdx%8 selects the XCD (round-robin dispatch); XCDs 0-3
// handle batch 0, XCDs 4-7 batch 1 -> each XCD's gather set is 2.56MB (fits L2).
// ---------------------------------------------------------------------------
union H4 { uint2 u; __half2 h[2]; };

#define SAMPLE4H(TT)                                                          \
    {                                                                         \
        const float tt = (TT);                                                \
        const float xs = bx + ax * tt;                                        \
        const float ys = by + ay * tt;                                        \
        const bool valid = (ys > -1.0f) & (ys < (float)H_) &                  \
                           (xs > -1.0f) & (xs < (float)W_);                   \
        float x = fminf(fmaxf(xs, 0.0f), (float)(W_ - 1));                    \
        float y = fminf(fmaxf(ys, 0.0f), (float)(H_ - 1));                    \
        int xl = min(max((int)floorf(x), 0), W_ - 2);                         \
        int yl = min(max((int)floorf(y), 0), H_ - 2);                         \
        const float lx = x - (float)xl;                                       \
        const float ly = y - (float)yl;                                       \
        const float hx = 1.0f - lx;                                           \
        const float hy = 1.0f - ly;                                           \
        const float w00 = hy * hx, w01 = hy * lx;                             \
        const float w10 = ly * hx, w11 = ly * lx;                             \
        const size_t cell = (size_t)(yl * W_ + xl) * 8;                       \
        H4 q00, q01, q10, q11;                                                \
        q00.u = fpu[cell];                                                    \
        q01.u = fpu[cell + 8];                                                \
        q10.u = fpu[cell + W_ * 8];                                           \
        q11.u = fpu[cell + (W_ + 1) * 8];                                     \
        const float2 a0 = __half22float2(q00.h[0]);                           \
        const float2 a1 = __half22float2(q00.h[1]);                           \
        const float2 b0 = __half22float2(q01.h[0]);                           \
        const float2 b1 = __half22float2(q01.h[1]);                           \
        const float2 c0 = __half22float2(q10.h[0]);                           \
        const float2 c1 = __half22float2(q10.h[1]);                           \
        const float2 d0 = __half22float2(q11.h[0]);                           \
        const float2 d1 = __half22float2(q11.h[1]);                           \
        float4 val;                                                           \
        val.x = w00 * a0.x + w01 * b0.x + w10 * c0.x + w11 * d0.x;            \
        val.y = w00 * a0.y + w01 * b0.y + w10 * c0.y + w11 * d0.y;            \
        val.z = w00 * a1.x + w01 * b1.x + w10 * c1.x + w11 * d1.x;            \
        val.w = w00 * a1.y + w01 * b1.y + w10 * c1.y + w11 * d1.y;            \
        if (!valid) { val.x = 0.0f; val.y = 0.0f; val.z = 0.0f; val.w = 0.0f; } \
        acc.x = fmaxf(acc.x, val.x);                                          \
        acc.y = fmaxf(acc.y, val.y);                                          \
        acc.z = fmaxf(acc.z, val.z);                                          \
        acc.w = fmaxf(acc.w, val.w);                                          \
    }

__global__ __launch_bounds__(256) void border_align_h4x_kernel(
    const __half* __restrict__ fT,     // [N*4][HW][32] fp16
    const float*  __restrict__ boxes,  // [N, HW, 4]
    const int*    __restrict__ pool_ptr,
    float*        __restrict__ out)    // [N, C, HW, 4]
{
    // XCD-affinity block remap: 1250 box-groups per batch, 4 XCDs per batch.
    const int xcd  = blockIdx.x & 7;
    const int slot = blockIdx.x >> 3;
    const int n    = xcd >> 2;                  // batch: XCD 0-3 -> 0, 4-7 -> 1
    const int bg   = slot * 4 + (xcd & 3);      // box-group within batch
    if (bg >= HW_ / 8) return;                  // 12 idle blocks (grid=2504)

    const int t  = threadIdx.x;
    const int v  = t & 7;                       // channel quad (c = 4v..4v+3)
    const int i  = (t >> 3) & 3;                // border
    const int bb = t >> 5;                      // 0..7 local box
    const int b  = bg * 8 + bb;                 // box within batch
    const int B  = n * HW_ + b;                 // global box

    const float4 box = reinterpret_cast<const float4*>(boxes)[B];
    const float x1 = box.x, y1 = box.y, x2 = box.z, y2 = box.w;
    const float bw = x2 - x1, bh = y2 - y1;

    const float bx = (i < 2) ? x1 : x2;
    const float by = (i < 2) ? y1 : y2;
    const float ax = (i == 0) ? bw : ((i == 2) ? -bw : 0.0f);
    const float ay = (i == 1) ? bh : ((i == 3) ? -bh : 0.0f);

    const uint2* __restrict__ fpu =
        reinterpret_cast<const uint2*>(fT + (size_t)(n * 4 + i) * HW_ * 32) + v;

    const int P = *pool_ptr;
    float4 acc = make_float4(-FLT_MAX, -FLT_MAX, -FLT_MAX, -FLT_MAX);
    if (P == 10) {
        #pragma unroll
        for (int k = 0; k <= 10; ++k) SAMPLE4H((float)k / 10.0f);
    } else {
        for (int k = 0; k <= P; ++k) SAMPLE4H((float)k / (float)P);
    }

    // LDS shuffle: sval[channel][bb*4+i], row padded to 36 (float4-aligned).
    __shared__ float sval[32 * 36];
    {
        const int col = bb * 4 + i;
        sval[(4 * v + 0) * 36 + col] = acc.x;
        sval[(4 * v + 1) * 36 + col] = acc.y;
        sval[(4 * v + 2) * 36 + col] = acc.z;
        sval[(4 * v + 3) * 36 + col] = acc.w;
    }
    __syncthreads();

    // Store: thread t -> channel cs = t>>3, box q = t&7 (4 borders = float4).
    const int cs = t >> 3;
    const int q  = t & 7;
    const float4 o = *reinterpret_cast<const float4*>(&sval[cs * 36 + q * 4]);
    float4* out4 = reinterpret_cast<float4*>(out);
    out4[(size_t)(n * C_ + cs) * HW_ + bg * 8 + q] = o;
}

// ---------------------------------------------------------------------------
// Fallback (round-1 kernel) if workspace is too small for the transpose.
// ---------------------------------------------------------------------------
__global__ __launch_bounds__(256) void border_align_kernel(
    const float* __restrict__ feat, const float* __restrict__ boxes,
    const int* __restrict__ pool_ptr, float* __restrict__ out)
{
    const int tid = blockIdx.x * blockDim.x + threadIdx.x;
    const int i    = tid & 3;
    int       rest = tid >> 2;
    const int b    = rest % HW_;
    rest /= HW_;
    const int c    = rest % C_;
    const int n    = rest / C_;

    const float4 box = reinterpret_cast<const float4*>(boxes)[n * HW_ + b];
    const float x1 = box.x, y1 = box.y, x2 = box.z, y2 = box.w;
    const float bw = x2 - x1, bh = y2 - y1;
    const float bx = (i < 2) ? x1 : x2;
    const float by = (i < 2) ? y1 : y2;
    const float ax = (i == 0) ? bw : ((i == 2) ? -bw : 0.0f);
    const float ay = (i == 1) ? bh : ((i == 3) ? -bh : 0.0f);
    const int ch = i * C_ + c;
    const float* __restrict__ fp = feat + (size_t)(n * C4_ + ch) * (H_ * W_);
    const int P = *pool_ptr;
    float acc = -FLT_MAX;
    for (int k = 0; k <= P; ++k) {
        const float tt = (float)k / (float)P;
        const float xs = bx + ax * tt;
        const float ys = by + ay * tt;
        const bool valid = (ys > -1.0f) & (ys < (float)H_) &
                           (xs > -1.0f) & (xs < (float)W_);
        float x = fminf(fmaxf(xs, 0.0f), (float)(W_ - 1));
        float y = fminf(fmaxf(ys, 0.0f), (float)(H_ - 1));
        int xl = min(max((int)floorf(x), 0), W_ - 2);
        int yl = min(max((int)floorf(y), 0), H_ - 2);
        const float lx = x - (float)xl, ly = y - (float)yl;
        const float hx = 1.0f - lx, hy = 1.0f - ly;
        const float* p00 = fp + yl * W_ + xl;
        float val = (hy * hx) * p00[0] + (hy * lx) * p00[1]
                  + (ly * hx) * p00[W_] + (ly * lx) * p00[W_ + 1];
        val = valid ? val : 0.0f;
        acc = fmaxf(acc, val);
    }
    out[tid] = acc;
}

extern "C" void kernel_launch(void* const* d_in, const int* in_sizes, int n_in,
                              void* d_out, int out_size, void* d_ws, size_t ws_size,
                              hipStream_t stream) {
    const float* feat  = (const float*)d_in[0];
    const float* boxes = (const float*)d_in[1];
    const int*   ps    = (const int*)d_in[2];
    float*       out   = (float*)d_out;

    const size_t needed = (size_t)N_ * 4 * HW_ * 32 * sizeof(__half); // 5.12 MB
    if (ws_size >= needed) {
        __half* fT = (__half*)d_ws;
        transpose_half_kernel<<<dim3((HW_ + 31) / 32, N_ * 4), dim3(32, 8), 0, stream>>>(feat, fT);
        // 1250 box-groups per batch; 313 slots x 8 XCD-lanes = 2504 blocks.
        border_align_h4x_kernel<<<313 * NXCD, 256, 0, stream>>>(fT, boxes, ps, out);
    } else {
        const int total = N_ * C_ * HW_ * 4;
        border_align_kernel<<<total / 256, 256, 0, stream>>>(feat, boxes, ps, out);
    }
}

// Round 6
// 27.641 us; speedup vs baseline: 5.1266x; 1.0299x over previous
//
#include <hip/hip_runtime.h>
#include <hip/hip_fp16.h>
#include <float.h>

// Problem constants (from reference setup_inputs)
#define N_   2
#define C4_  128
#define C_   32      // C4/4
#define H_   100
#define W_   100
#define HW_  10000   // H*W boxes per batch (also H*W positions)
#define NXCD 8

// ---------------------------------------------------------------------------
// Pass 1: transpose + compress feat [N, C4, H, W] (fp32) -> fT [N*4][HW][32] (fp16)
// ---------------------------------------------------------------------------
__global__ __launch_bounds__(256) void transpose_half_kernel(
    const float* __restrict__ feat, __half* __restrict__ fT)
{
    __shared__ float tile[32][33];
    const int g  = blockIdx.y;          // 0..7  (n*4 + i)
    const int p0 = blockIdx.x * 32;     // position tile base
    const int tx = threadIdx.x;         // 0..31
    const int ty = threadIdx.y;         // 0..7

    const float* src = feat + (size_t)g * 32 * HW_;  // == (n*C4 + i*32)*HW
    #pragma unroll
    for (int cc = 0; cc < 32; cc += 8) {
        const int c = cc + ty;
        const int p = p0 + tx;
        tile[c][tx] = (p < HW_) ? src[(size_t)c * HW_ + p] : 0.0f;
    }
    __syncthreads();

    const int t    = ty * 32 + tx;      // 0..255
    const int pair = t & 15;            // channel pair (2*pair, 2*pair+1)
    const int prow = t >> 4;            // 0..15 local position
    __half2* dst = reinterpret_cast<__half2*>(fT + (size_t)g * HW_ * 32);
    #pragma unroll
    for (int pp = 0; pp < 32; pp += 16) {
        const int p = p0 + prow + pp;
        if (p < HW_) {
            const float a = tile[2 * pair][prow + pp];
            const float b = tile[2 * pair + 1][prow + pp];
            dst[(size_t)p * 16 + pair] = __floats2half2_rn(a, b);
        }
    }
}

// ---------------------------------------------------------------------------
// Pass 2: border-align on fp16 transposed features, 8 channels per thread.
// Block = 256 threads = 16 boxes x 4 borders x 4 channel-octets.
// Lane layout: v = t&3 (channel octet), i = (t>>2)&3 (border), bb = t>>4 (box).
// Each corner load: 4 lanes x 16B = one 64B line.
// XCD-affinity: blockIdx%8 -> XCD; XCDs 0-3 batch 0, XCDs 4-7 batch 1.
// ---------------------------------------------------------------------------
union H8 { float4 f4; __half2 h[4]; };

#define SAMPLE8H(TT)                                                          \
    {                                                                         \
        const float tt = (TT);                                                \
        const float xs = bx + ax * tt;                                        \
        const float ys = by + ay * tt;                                        \
        const bool valid = (ys > -1.0f) & (ys < (float)H_) &                  \
                           (xs > -1.0f) & (xs < (float)W_);                   \
        float x = fminf(fmaxf(xs, 0.0f), (float)(W_ - 1));                    \
        float y = fminf(fmaxf(ys, 0.0f), (float)(H_ - 1));                    \
        int xl = min(max((int)floorf(x), 0), W_ - 2);                         \
        int yl = min(max((int)floorf(y), 0), H_ - 2);                         \
        const float lx = x - (float)xl;                                       \
        const float ly = y - (float)yl;                                       \
        const float hx = 1.0f - lx;                                           \
        const float hy = 1.0f - ly;                                           \
        const float w00 = hy * hx, w01 = hy * lx;                             \
        const float w10 = ly * hx, w11 = ly * lx;                             \
        const size_t cell = (size_t)(yl * W_ + xl) * 4;                       \
        H8 q00, q01, q10, q11;                                                \
        q00.f4 = fpq[cell];                                                   \
        q01.f4 = fpq[cell + 4];                                               \
        q10.f4 = fpq[cell + W_ * 4];                                          \
        q11.f4 = fpq[cell + (W_ + 1) * 4];                                    \
        _Pragma("unroll")                                                     \
        for (int j = 0; j < 4; ++j) {                                         \
            const float2 a = __half22float2(q00.h[j]);                        \
            const float2 b2 = __half22float2(q01.h[j]);                       \
            const float2 c2 = __half22float2(q10.h[j]);                       \
            const float2 d2 = __half22float2(q11.h[j]);                       \
            float vx = w00 * a.x + w01 * b2.x + w10 * c2.x + w11 * d2.x;      \
            float vy = w00 * a.y + w01 * b2.y + w10 * c2.y + w11 * d2.y;      \
            vx = valid ? vx : 0.0f;                                           \
            vy = valid ? vy : 0.0f;                                           \
            acc[2 * j]     = fmaxf(acc[2 * j], vx);                           \
            acc[2 * j + 1] = fmaxf(acc[2 * j + 1], vy);                       \
        }                                                                     \
    }

__global__ __launch_bounds__(256) void border_align_h8x_kernel(
    const __half* __restrict__ fT,     // [N*4][HW][32] fp16
    const float*  __restrict__ boxes,  // [N, HW, 4]
    const int*    __restrict__ pool_ptr,
    float*        __restrict__ out)    // [N, C, HW, 4]
{
    // XCD-affinity remap: 625 16-box groups per batch, 4 XCDs per batch.
    const int xcd  = blockIdx.x & 7;
    const int slot = blockIdx.x >> 3;
    const int n    = xcd >> 2;                  // batch
    const int bg   = slot * 4 + (xcd & 3);      // box-group within batch
    if (bg >= HW_ / 16) return;                 // grid = 157*8 = 1256, 6 idle

    const int t  = threadIdx.x;
    const int v  = t & 3;                       // channel octet (c = 8v..8v+7)
    const int i  = (t >> 2) & 3;                // border
    const int bb = t >> 4;                      // 0..15 local box
    const int b  = bg * 16 + bb;                // box within batch
    const int B  = n * HW_ + b;                 // global box

    const float4 box = reinterpret_cast<const float4*>(boxes)[B];
    const float x1 = box.x, y1 = box.y, x2 = box.z, y2 = box.w;
    const float bw = x2 - x1, bh = y2 - y1;

    const float bx = (i < 2) ? x1 : x2;
    const float by = (i < 2) ? y1 : y2;
    const float ax = (i == 0) ? bw : ((i == 2) ? -bw : 0.0f);
    const float ay = (i == 1) ? bh : ((i == 3) ? -bh : 0.0f);

    // plane base in float4 (16B) units; v selects the channel octet
    const float4* __restrict__ fpq =
        reinterpret_cast<const float4*>(fT + (size_t)(n * 4 + i) * HW_ * 32) + v;

    const int P = *pool_ptr;
    float acc[8];
    #pragma unroll
    for (int j = 0; j < 8; ++j) acc[j] = -FLT_MAX;

    if (P == 10) {
        #pragma unroll
        for (int k = 0; k <= 10; ++k) SAMPLE8H((float)k / 10.0f);
    } else {
        for (int k = 0; k <= P; ++k) SAMPLE8H((float)k / (float)P);
    }

    // LDS shuffle: sval[channel][box*4 + border], row stride 68 (16B-aligned).
    __shared__ float sval[32 * 68];
    {
        const int col = bb * 4 + i;             // 0..63
        #pragma unroll
        for (int j = 0; j < 8; ++j) sval[(8 * v + j) * 68 + col] = acc[j];
    }
    __syncthreads();

    // Store: thread t -> channel cs = t>>3, boxes q and q+8 (float4 = 4 borders).
    const int cs = t >> 3;                      // 0..31
    const int q  = t & 7;                       // 0..7
    const float4 o0 = *reinterpret_cast<const float4*>(&sval[cs * 68 + q * 4]);
    const float4 o1 = *reinterpret_cast<const float4*>(&sval[cs * 68 + (q + 8) * 4]);
    float4* out4 = reinterpret_cast<float4*>(out);
    const size_t base = (size_t)(n * C_ + cs) * HW_ + bg * 16;
    out4[base + q]     = o0;
    out4[base + q + 8] = o1;
}

// ---------------------------------------------------------------------------
// Fallback (round-1 kernel) if workspace is too small for the transpose.
// ---------------------------------------------------------------------------
__global__ __launch_bounds__(256) void border_align_kernel(
    const float* __restrict__ feat, const float* __restrict__ boxes,
    const int* __restrict__ pool_ptr, float* __restrict__ out)
{
    const int tid = blockIdx.x * blockDim.x + threadIdx.x;
    const int i    = tid & 3;
    int       rest = tid >> 2;
    const int b    = rest % HW_;
    rest /= HW_;
    const int c    = rest % C_;
    const int n    = rest / C_;

    const float4 box = reinterpret_cast<const float4*>(boxes)[n * HW_ + b];
    const float x1 = box.x, y1 = box.y, x2 = box.z, y2 = box.w;
    const float bw = x2 - x1, bh = y2 - y1;
    const float bx = (i < 2) ? x1 : x2;
    const float by = (i < 2) ? y1 : y2;
    const float ax = (i == 0) ? bw : ((i == 2) ? -bw : 0.0f);
    const float ay = (i == 1) ? bh : ((i == 3) ? -bh : 0.0f);
    const int ch = i * C_ + c;
    const float* __restrict__ fp = feat + (size_t)(n * C4_ + ch) * (H_ * W_);
    const int P = *pool_ptr;
    float acc = -FLT_MAX;
    for (int k = 0; k <= P; ++k) {
        const float tt = (float)k / (float)P;
        const float xs = bx + ax * tt;
        const float ys = by + ay * tt;
        const bool valid = (ys > -1.0f) & (ys < (float)H_) &
                           (xs > -1.0f) & (xs < (float)W_);
        float x = fminf(fmaxf(xs, 0.0f), (float)(W_ - 1));
        float y = fminf(fmaxf(ys, 0.0f), (float)(H_ - 1));
        int xl = min(max((int)floorf(x), 0), W_ - 2);
        int yl = min(max((int)floorf(y), 0), H_ - 2);
        const float lx = x - (float)xl, ly = y - (float)yl;
        const float hx = 1.0f - lx, hy = 1.0f - ly;
        const float* p00 = fp + yl * W_ + xl;
        float val = (hy * hx) * p00[0] + (hy * lx) * p00[1]
                  + (ly * hx) * p00[W_] + (ly * lx) * p00[W_ + 1];
        val = valid ? val : 0.0f;
        acc = fmaxf(acc, val);
    }
    out[tid] = acc;
}

extern "C" void kernel_launch(void* const* d_in, const int* in_sizes, int n_in,
                              void* d_out, int out_size, void* d_ws, size_t ws_size,
                              hipStream_t stream) {
    const float* feat  = (const float*)d_in[0];
    const float* boxes = (const float*)d_in[1];
    const int*   ps    = (const int*)d_in[2];
    float*       out   = (float*)d_out;

    const size_t needed = (size_t)N_ * 4 * HW_ * 32 * sizeof(__half); // 5.12 MB
    if (ws_size >= needed) {
        __half* fT = (__half*)d_ws;
        transpose_half_kernel<<<dim3((HW_ + 31) / 32, N_ * 4), dim3(32, 8), 0, stream>>>(feat, fT);
        // 625 16-box groups per batch; 157 slots x 8 XCD-lanes = 1256 blocks.
        border_align_h8x_kernel<<<157 * NXCD, 256, 0, stream>>>(fT, boxes, ps, out);
    } else {
        const int total = N_ * C_ * HW_ * 4;
        border_align_kernel<<<total / 256, 256, 0, stream>>>(feat, boxes, ps, out);
    }
}